// Round 1
// 277.949 us; speedup vs baseline: 1.0308x; 1.0308x over previous
//
#include <hip/hip_runtime.h>
#include <hip/hip_bf16.h>
#include <math.h>

#define N_NODES 6144
#define NFEAT 512
#define NHID 256
#define NHEADS 4
#define DHEAD 64
#define NEMBED 128
#define LRELU_ALPHA 0.2f
#define MAXC 256          // CSR capacity/row; degree ~Binom(6144,1%): mean 61, max~100
#define ASTRIDE 20        // As row pad: breaks 4-way read conflict, keeps 16B align

// round-to-nearest-even fp32 -> bf16
static __device__ __forceinline__ unsigned short f2bf(float f) {
    unsigned u = __float_as_uint(f);
    unsigned r = (u + 0x7FFFu + ((u >> 16) & 1u)) >> 16;
    return (unsigned short)r;
}

// ---------------------------------------------------------------------------
// Kernel 1: grid (96, 68).
//  y<4 : Wh[h]=x.W[h] 64x64-tile fp32 GEMM + fused s/t epilogue.
//        Wh is stored ONLY as bf16 (halves store bytes + K2 gather bytes);
//        s/t logits computed from the fp32 accumulators -> softmax unchanged.
//  y>=4: ONE adjacency row per block, LDS-free flat scan -> CSR (atomics).
// ---------------------------------------------------------------------------
__global__ __launch_bounds__(256) void gemm_scan(const float* __restrict__ x,
                                                 const float* __restrict__ W,
                                                 const float* __restrict__ a_src,
                                                 const float* __restrict__ a_dst,
                                                 const int* __restrict__ adj,
                                                 unsigned short* __restrict__ Whb,
                                                 float* __restrict__ s_arr,
                                                 float* __restrict__ t_arr,
                                                 int* __restrict__ cnt_g,
                                                 unsigned short* __restrict__ nbr_g) {
    __shared__ float As[64][ASTRIDE];
    __shared__ float Bs[16][64];
    const int tid = threadIdx.x;

    if (blockIdx.y < NHEADS) {
        // ---------------- GEMM path ----------------
        const int tx = tid & 15;
        const int ty = tid >> 4;
        const int row0 = blockIdx.x * 64;
        const int h = blockIdx.y;
        const float* Bp = W + (size_t)h * NFEAT * DHEAD;

        float acc[4][4] = {};

        for (int k0 = 0; k0 < NFEAT; k0 += 16) {
            {
                const int r = tid >> 2, kq = tid & 3;
                const float4 v = *(const float4*)(x + (size_t)(row0 + r) * NFEAT + k0 + kq * 4);
                *(float4*)&As[r][kq * 4] = v;
            }
            {
                const int kk = tid >> 4, cq = tid & 15;
                const float4 v = *(const float4*)(Bp + (size_t)(k0 + kk) * DHEAD + cq * 4);
                *(float4*)&Bs[kk][cq * 4] = v;
            }
            __syncthreads();
#pragma unroll
            for (int kk = 0; kk < 16; kk++) {
                float a[4], b[4];
#pragma unroll
                for (int i = 0; i < 4; i++) a[i] = As[ty * 4 + i][kk];
#pragma unroll
                for (int j = 0; j < 4; j++) b[j] = Bs[kk][tx * 4 + j];
#pragma unroll
                for (int i = 0; i < 4; i++)
#pragma unroll
                    for (int j = 0; j < 4; j++) acc[i][j] += a[i] * b[j];
            }
            __syncthreads();
        }
        // bf16 Wh store (8 B/thread/row)
#pragma unroll
        for (int i = 0; i < 4; i++) {
            const int row = row0 + ty * 4 + i;
            ushort4 w;
            w.x = f2bf(acc[i][0]);
            w.y = f2bf(acc[i][1]);
            w.z = f2bf(acc[i][2]);
            w.w = f2bf(acc[i][3]);
            *(ushort4*)(Whb + ((size_t)h * N_NODES + row) * DHEAD + tx * 4) = w;
        }
        // fused s/t epilogue (fp32 accumulators -> logits stay fp32-precise)
        float a4s[4], a4d[4];
#pragma unroll
        for (int j = 0; j < 4; j++) {
            a4s[j] = a_src[h * DHEAD + tx * 4 + j];
            a4d[j] = a_dst[h * DHEAD + tx * 4 + j];
        }
#pragma unroll
        for (int i = 0; i < 4; i++) {
            float ps = acc[i][0] * a4s[0] + acc[i][1] * a4s[1] +
                       acc[i][2] * a4s[2] + acc[i][3] * a4s[3];
            float pt = acc[i][0] * a4d[0] + acc[i][1] * a4d[1] +
                       acc[i][2] * a4d[2] + acc[i][3] * a4d[3];
#pragma unroll
            for (int off = 1; off < 16; off <<= 1) {
                ps += __shfl_xor(ps, off);
                pt += __shfl_xor(pt, off);
            }
            if (tx == 0) {
                const int row = row0 + ty * 4 + i;
                s_arr[h * N_NODES + row] = ps;
                t_arr[h * N_NODES + row] = pt;
            }
        }
    } else {
        // ---------------- scan path: one row per block, LDS-free ----------------
        const int r = (blockIdx.y - NHEADS) * gridDim.x + blockIdx.x; // 0..6143
        const int* arow = adj + (size_t)r * N_NODES;
        unsigned short* nrow = nbr_g + (size_t)r * MAXC;
        int* cp = cnt_g + r;
#pragma unroll
        for (int it = 0; it < 6; ++it) {
            const int j0 = it * 1024 + tid * 4;
            const int4 v = *(const int4*)(arow + j0);
            const int n = (v.x != 0) + (v.y != 0) + (v.z != 0) + (v.w != 0);
            if (n) {
                int base = atomicAdd(cp, n);
                if (v.x) { if (base < MAXC) nrow[base] = (unsigned short)j0; ++base; }
                if (v.y) { if (base < MAXC) nrow[base] = (unsigned short)(j0 + 1); ++base; }
                if (v.z) { if (base < MAXC) nrow[base] = (unsigned short)(j0 + 2); ++base; }
                if (v.w) { if (base < MAXC) nrow[base] = (unsigned short)(j0 + 3); }
            }
        }
    }
}

// ---------------------------------------------------------------------------
// Kernel 2: CSR-consuming attention. Block = dst node i; wave h = head h.
// bf16 Wh gather, 2 neighbor rows per wave load:
//   a bf16 row is 128 B = 32 lanes x 4 B -> lanes 0-31 take neighbor k,
//   lanes 32-63 take neighbor k+1; each lane accumulates a d-pair; one
//   __shfl_xor(.,32) merges the halves at the end. Gather instrs x0.5,
//   bytes x0.5 vs fp32 one-row-per-load.
// ---------------------------------------------------------------------------
__global__ __launch_bounds__(256) void attn_agg(const int* __restrict__ adj,
                                                const unsigned short* __restrict__ Whb,
                                                const float* __restrict__ s_arr,
                                                const float* __restrict__ t_arr,
                                                const int* __restrict__ cnt_g,
                                                const unsigned short* __restrict__ nbr_g,
                                                float* __restrict__ hcat) {
    __shared__ unsigned short nbr[MAXC];
    __shared__ float p_s[NHEADS][MAXC];
    const int i = blockIdx.x;
    const int tid = threadIdx.x;
    const int h = tid >> 6;
    const int lane = tid & 63;
    const int half = lane >> 5;        // which neighbor of the pair this lane serves
    const int dp = (lane & 31) * 2;    // d-pair base this lane accumulates
    const int c = cnt_g[i];
    const unsigned short* wp = Whb + (size_t)h * N_NODES * DHEAD;

    float r0 = 0.0f, r1 = 0.0f, l = 1.0f;
    bool combine = true;
    if (c > 0 && c <= MAXC) {
        for (int k = tid; k < c; k += 256) nbr[k] = nbr_g[(size_t)i * MAXC + k];
        __syncthreads();

        const float s_h = s_arr[h * N_NODES + i];
        const float* tp = t_arr + (size_t)h * N_NODES;
        float m = -INFINITY;
        for (int k = lane; k < c; k += 64) {
            float e = s_h + tp[nbr[k]];
            e = e >= 0.0f ? e : LRELU_ALPHA * e;
            p_s[h][k] = e;
            m = fmaxf(m, e);
        }
#pragma unroll
        for (int off = 32; off > 0; off >>= 1) m = fmaxf(m, __shfl_xor(m, off));
        float ls = 0.0f;
        for (int k = lane; k < c; k += 64) {
            const float p = __expf(p_s[h][k] - m);
            p_s[h][k] = p;
            ls += p;
        }
#pragma unroll
        for (int off = 32; off > 0; off >>= 1) ls += __shfl_xor(ls, off);
        l = ls;
        // p_s[h] is wave-private: no barrier needed.

        float ax[8] = {0.f, 0.f, 0.f, 0.f, 0.f, 0.f, 0.f, 0.f};
        float ay[8] = {0.f, 0.f, 0.f, 0.f, 0.f, 0.f, 0.f, 0.f};
        int k = 0;
        for (; k + 16 <= c; k += 16) {
#pragma unroll
            for (int s2 = 0; s2 < 8; ++s2) {
                const int kk = k + 2 * s2 + half;
                const int j = nbr[kk];
                const float p = p_s[h][kk];
                const unsigned w = *(const unsigned*)(wp + (size_t)j * DHEAD + dp);
                ax[s2] += p * __uint_as_float(w << 16);
                ay[s2] += p * __uint_as_float(w & 0xffff0000u);
            }
        }
        for (; k < c; k += 2) {
            const int kk = k + half;
            int j = nbr[k];
            float p = 0.0f;
            if (kk < c) { j = nbr[kk]; p = p_s[h][kk]; }
            const unsigned w = *(const unsigned*)(wp + (size_t)j * DHEAD + dp);
            ax[0] += p * __uint_as_float(w << 16);
            ay[0] += p * __uint_as_float(w & 0xffff0000u);
        }
        r0 = ((ax[0] + ax[1]) + (ax[2] + ax[3])) + ((ax[4] + ax[5]) + (ax[6] + ax[7]));
        r1 = ((ay[0] + ay[1]) + (ay[2] + ay[3])) + ((ay[4] + ay[5]) + (ay[6] + ay[7]));
    } else if (c == 0) {
        // empty row: softmax over uniform -9e15 logits -> mean of Wh
        for (int j = half; j < N_NODES; j += 2) {
            const unsigned w = *(const unsigned*)(wp + (size_t)j * DHEAD + dp);
            r0 += __uint_as_float(w << 16);
            r1 += __uint_as_float(w & 0xffff0000u);
        }
        l = (float)N_NODES;
    } else {
        // c > MAXC: serial online-softmax rescan (never expected at 1% density)
        combine = false;
        const int* arow = adj + (size_t)i * N_NODES;
        const float s_h = s_arr[h * N_NODES + i];
        const float* tp = t_arr + (size_t)h * N_NODES;
        float m = -INFINITY, ll = 0.0f;
        for (int j = 0; j < N_NODES; j++) {
            if (arow[j]) {
                float e = s_h + tp[j];
                e = e >= 0.0f ? e : LRELU_ALPHA * e;
                const float m_new = fmaxf(m, e);
                const float scale = __expf(m - m_new);
                const float p = __expf(e - m_new);
                ll = ll * scale + p;
                const unsigned w = *(const unsigned*)(wp + (size_t)j * DHEAD + dp);
                r0 = r0 * scale + p * __uint_as_float(w << 16);
                r1 = r1 * scale + p * __uint_as_float(w & 0xffff0000u);
                m = m_new;
            }
        }
        l = ll;
    }
    if (combine) {
        r0 += __shfl_xor(r0, 32);
        r1 += __shfl_xor(r1, 32);
    }
    float hx = r0 / l, hy = r1 / l;
    hx = hx > 0.0f ? hx : expm1f(hx);
    hy = hy > 0.0f ? hy : expm1f(hy);
    if (lane < 32) {
        *(float2*)(hcat + (size_t)i * NHID + h * DHEAD + dp) = make_float2(hx, hy);
    }
}

// ---------------------------------------------------------------------------
// Kernel 3: out = elu(hcat @ lin_w^T + b)
// ---------------------------------------------------------------------------
__global__ __launch_bounds__(256) void out_gemm(const float* __restrict__ hcat,
                                                const float* __restrict__ lin_w,
                                                const float* __restrict__ lin_b,
                                                float* __restrict__ out) {
    __shared__ float As[64][ASTRIDE * 4];
    __shared__ float Bs[16][64];
    const int tid = threadIdx.x;
    const int tx = tid & 15;
    const int ty = tid >> 4;
    const int row0 = blockIdx.x * 64;
    const int c0 = blockIdx.y * 64;

    float acc[4][4] = {};

    for (int k0 = 0; k0 < NHID; k0 += 16) {
        {
            const int r = tid >> 2, kq = tid & 3;
            const float4 v = *(const float4*)(hcat + (size_t)(row0 + r) * NHID + k0 + kq * 4);
            *(float4*)&As[r][kq * 4] = v;
        }
        {
            const int cc = tid & 63, kq = tid >> 6;
            const float4 v = *(const float4*)(lin_w + (size_t)(c0 + cc) * NHID + k0 + kq * 4);
            Bs[kq * 4 + 0][cc] = v.x;
            Bs[kq * 4 + 1][cc] = v.y;
            Bs[kq * 4 + 2][cc] = v.z;
            Bs[kq * 4 + 3][cc] = v.w;
        }
        __syncthreads();
#pragma unroll
        for (int kk = 0; kk < 16; kk++) {
            float a[4], b[4];
#pragma unroll
            for (int i = 0; i < 4; i++) a[i] = As[ty * 4 + i][kk];
#pragma unroll
            for (int j = 0; j < 4; j++) b[j] = Bs[kk][tx * 4 + j];
#pragma unroll
            for (int i = 0; i < 4; i++)
#pragma unroll
                for (int j = 0; j < 4; j++) acc[i][j] += a[i] * b[j];
        }
        __syncthreads();
    }
#pragma unroll
    for (int i = 0; i < 4; i++) {
        const int row = row0 + ty * 4 + i;
        float v[4];
#pragma unroll
        for (int j = 0; j < 4; j++) {
            const int col = c0 + tx * 4 + j;
            float val = acc[i][j] + lin_b[col];
            v[j] = val > 0.0f ? val : expm1f(val);
        }
        *(float4*)(out + (size_t)row * NEMBED + c0 + tx * 4) =
            make_float4(v[0], v[1], v[2], v[3]);
    }
}

extern "C" void kernel_launch(void* const* d_in, const int* in_sizes, int n_in,
                              void* d_out, int out_size, void* d_ws, size_t ws_size,
                              hipStream_t stream) {
    const float* x     = (const float*)d_in[0];
    const int*   adj   = (const int*)d_in[1];
    const float* W     = (const float*)d_in[2];
    const float* a_src = (const float*)d_in[3];
    const float* a_dst = (const float*)d_in[4];
    const float* lin_w = (const float*)d_in[5];
    const float* lin_b = (const float*)d_in[6];
    float* out = (float*)d_out;

    unsigned short* Whb = (unsigned short*)d_ws;                  // H*N*D bf16 (3.1 MB)
    float* s    = (float*)(Whb + (size_t)NHEADS * N_NODES * DHEAD);
    float* t    = s + (size_t)NHEADS * N_NODES;
    float* hcat = t + (size_t)NHEADS * N_NODES;                   // N*NHID floats
    int* cnt_g  = (int*)(hcat + (size_t)N_NODES * NHID);          // N ints
    unsigned short* nbr_g = (unsigned short*)(cnt_g + N_NODES);   // N*MAXC ushort

    hipMemsetAsync(cnt_g, 0, N_NODES * sizeof(int), stream);
    gemm_scan<<<dim3(96, NHEADS + 64), 256, 0, stream>>>(
        x, W, a_src, a_dst, adj, Whb, s, t, cnt_g, nbr_g);
    attn_agg<<<N_NODES, 256, 0, stream>>>(adj, Whb, s, t, cnt_g, nbr_g, hcat);
    out_gemm<<<dim3(N_NODES / 64, NEMBED / 64), 256, 0, stream>>>(hcat, lin_w, lin_b, out);
}